// Round 15
// baseline (485.923 us; speedup 1.0000x reference)
//
#include <hip/hip_runtime.h>
#include <hip/hip_bf16.h>
#include <hip/hip_fp16.h>

#define CDIV(a,b) (((a)+(b)-1)/(b))

typedef float f32x4 __attribute__((ext_vector_type(4)));
typedef int   i32x4 __attribute__((ext_vector_type(4)));
typedef unsigned int u32x2 __attribute__((ext_vector_type(2)));

__device__ __forceinline__ void mfma16(f32x4& d, i32x4 a, i32x4 b) {
  asm("v_mfma_f32_16x16x32_bf16 %0, %1, %2, %0" : "+v"(d) : "v"(a), "v"(b));
}

__device__ __forceinline__ unsigned short bf16r(float x) {
  return __builtin_bit_cast(unsigned short, __float2bfloat16(x));
}
__device__ __forceinline__ float bf16f(unsigned short u) {
  unsigned int w_ = (unsigned int)u << 16;
  return __builtin_bit_cast(float, w_);
}

// NUMERICS LEDGER (measured):
//  - W1/W2 bf16 hi/lo + x hi/lo + h1 single-plane -> absmax 5.96e-8 (floor)
//  - x single-plane -> 2.86e-6 FAIL (R10). Input x MUST stay hi/lo split.
//  - h1 lo-plane dropped -> invisible (R9). Post-layer-1 rounding is cheap.
// PERF LEDGER:
//  - R6/R7: fragment-ordered weight packs failed unexplainably — banned.
//  - R11: degree-sort w/ global atomic cursors = +500us atomics. Banned.
//  - R4/R12/R13: launch_bounds-induced VGPR caps cause silent spill
//    (R13: (512,4)+nt=5 -> VGPR 64, 10MB scratch WRITE). LDS already limits
//    k_mlp to 2 blocks/CU, so use (512,2): VGPR headroom costs no occupancy.
//  - k_mlp lever that works: fewer blocks = less weight refetch
//    (3125->2084->1563->1250 blocks: 205->146->118->107us).

// ---------------- CSR build ----------------
__global__ __launch_bounds__(256) void k_count(const int* __restrict__ dst,
                                               int* __restrict__ cnt, int E) {
  int e = blockIdx.x * blockDim.x + threadIdx.x;
  if (e < E) atomicAdd(&cnt[dst[e]], 1);
}

__global__ __launch_bounds__(256) void k_scan1(const int* __restrict__ cnt,
                                               int* __restrict__ rowptr,
                                               int* __restrict__ blockSums, int N) {
  __shared__ int sdata[256];
  const int t = threadIdx.x;
  const int base = blockIdx.x * 1024;
  int v[4]; int local = 0;
#pragma unroll
  for (int i = 0; i < 4; i++) {
    int idx = base + t * 4 + i;
    v[i] = (idx < N) ? cnt[idx] : 0;
    local += v[i];
  }
  sdata[t] = local;
  __syncthreads();
  for (int off = 1; off < 256; off <<= 1) {
    int x = (t >= off) ? sdata[t - off] : 0;
    __syncthreads();
    sdata[t] += x;
    __syncthreads();
  }
  if (t == 255) blockSums[blockIdx.x] = sdata[255];
  int run = sdata[t] - local;
#pragma unroll
  for (int i = 0; i < 4; i++) {
    int idx = base + t * 4 + i;
    if (idx < N) rowptr[idx] = run;
    run += v[i];
  }
}

__global__ __launch_bounds__(256) void k_scan2(int* blockSums, int NB) {
  __shared__ int sdata[256];
  int t = threadIdx.x;
  int v = (t < NB) ? blockSums[t] : 0;
  sdata[t] = v;
  __syncthreads();
  for (int off = 1; off < 256; off <<= 1) {
    int x = (t >= off) ? sdata[t - off] : 0;
    __syncthreads();
    sdata[t] += x;
    __syncthreads();
  }
  if (t < NB) blockSums[t] = sdata[t] - v;
}

__global__ __launch_bounds__(256) void k_scan3(int* __restrict__ rowptr,
                                               const int* __restrict__ blockSums,
                                               int N, int E) {
  int idx = blockIdx.x * blockDim.x + threadIdx.x;
  if (idx < N) rowptr[idx] += blockSums[idx >> 10];
  if (idx == 0) rowptr[N] = E;
}

__global__ __launch_bounds__(256) void k_fill(const int* __restrict__ src,
                                              const int* __restrict__ dst,
                                              const int* __restrict__ rowptr,
                                              int* __restrict__ cursor,
                                              int* __restrict__ colidx, int E) {
  int e = blockIdx.x * blockDim.x + threadIdx.x;
  if (e < E) {
    int d = dst[e];
    int pos = rowptr[d] + atomicAdd(&cursor[d], 1);
    colidx[pos] = src[e];
  }
}

__global__ __launch_bounds__(256) void k_dinv(const int* __restrict__ cnt,
                                              float* __restrict__ dinv, int N) {
  int i = blockIdx.x * blockDim.x + threadIdx.x;
  if (i < N) dinv[i] = rsqrtf((float)cnt[i] + 1.0f);
}

// ---------------- GCN layer ----------------
// y[n][c] = half( dinv[n] * sum_k x[n][k] * W[k][c] )   (fp16 table, 64 B/row)
__global__ __launch_bounds__(256) void k_xw(const float* __restrict__ x,
                                            const float* __restrict__ W,
                                            const float* __restrict__ dinv,
                                            unsigned short* __restrict__ y, int N) {
  __shared__ float Ws[1024];
  int t = threadIdx.x;
#pragma unroll
  for (int i = 0; i < 4; i++) Ws[t + i * 256] = W[t + i * 256];
  __syncthreads();
  int gid = blockIdx.x * blockDim.x + t;
  int n = gid >> 4, c = (gid & 15) * 2;
  if (n < N) {
    const float4* xr4 = (const float4*)(x + (size_t)n * 32);
    float a0 = 0.f, a1 = 0.f;
#pragma unroll
    for (int k4 = 0; k4 < 8; k4++) {
      float4 xv = xr4[k4];
      int k = k4 * 4;
      a0 = fmaf(xv.x, Ws[(k + 0) * 32 + c], a0); a1 = fmaf(xv.x, Ws[(k + 0) * 32 + c + 1], a1);
      a0 = fmaf(xv.y, Ws[(k + 1) * 32 + c], a0); a1 = fmaf(xv.y, Ws[(k + 1) * 32 + c + 1], a1);
      a0 = fmaf(xv.z, Ws[(k + 2) * 32 + c], a0); a1 = fmaf(xv.z, Ws[(k + 2) * 32 + c + 1], a1);
      a0 = fmaf(xv.w, Ws[(k + 3) * 32 + c], a0); a1 = fmaf(xv.w, Ws[(k + 3) * 32 + c + 1], a1);
    }
    float dn = dinv[n];
    __half2 h = __floats2half2_rn(a0 * dn, a1 * dn);
    *(__half2*)&y[(size_t)gid * 2] = h;
  }
}

__device__ __forceinline__ void acc8(float* acc, uint4 v) {
  float2 f;
  f = __half22float2(__builtin_bit_cast(__half2, v.x)); acc[0] += f.x; acc[1] += f.y;
  f = __half22float2(__builtin_bit_cast(__half2, v.y)); acc[2] += f.x; acc[3] += f.y;
  f = __half22float2(__builtin_bit_cast(__half2, v.z)); acc[4] += f.x; acc[5] += f.y;
  f = __half22float2(__builtin_bit_cast(__half2, v.w)); acc[6] += f.x; acc[7] += f.y;
}

// out[n] = relu(dinv[n]*(sum_{s in N(n)} y[s] + y[n]) + b)
// R10-proven exact config: 4 lanes/node, 16/8/4/scalar unroll tails,
// DEFAULT launch bounds (VGPR ~100 — capping spills, see ledger).
__global__ __launch_bounds__(256) void k_agg(const unsigned short* __restrict__ y,
                                             const int* __restrict__ rowptr,
                                             const int* __restrict__ colidx,
                                             const float* __restrict__ dinv,
                                             const float* __restrict__ b,
                                             float* __restrict__ out, int N) {
  int t = threadIdx.x;
  int q = t & 3;
  int n = blockIdx.x * 64 + (t >> 2);
  if (n >= N) return;
  const uint4* yrow = (const uint4*)y;
  float acc[8];
  {
    uint4 v = yrow[(size_t)n * 4 + q];  // self-loop term
    float2 f;
    f = __half22float2(__builtin_bit_cast(__half2, v.x)); acc[0] = f.x; acc[1] = f.y;
    f = __half22float2(__builtin_bit_cast(__half2, v.y)); acc[2] = f.x; acc[3] = f.y;
    f = __half22float2(__builtin_bit_cast(__half2, v.z)); acc[4] = f.x; acc[5] = f.y;
    f = __half22float2(__builtin_bit_cast(__half2, v.w)); acc[6] = f.x; acc[7] = f.y;
  }
  int beg = rowptr[n], end = rowptr[n + 1];
  int j = beg;
  for (; j + 16 <= end; j += 16) {
    uint4 v[16];
#pragma unroll
    for (int u = 0; u < 16; u++) v[u] = yrow[(size_t)colidx[j + u] * 4 + q];
#pragma unroll
    for (int u = 0; u < 16; u++) acc8(acc, v[u]);
  }
  for (; j + 8 <= end; j += 8) {
    uint4 v[8];
#pragma unroll
    for (int u = 0; u < 8; u++) v[u] = yrow[(size_t)colidx[j + u] * 4 + q];
#pragma unroll
    for (int u = 0; u < 8; u++) acc8(acc, v[u]);
  }
  for (; j + 4 <= end; j += 4) {
    uint4 v[4];
#pragma unroll
    for (int u = 0; u < 4; u++) v[u] = yrow[(size_t)colidx[j + u] * 4 + q];
#pragma unroll
    for (int u = 0; u < 4; u++) acc8(acc, v[u]);
  }
  for (; j < end; j++) {
    uint4 v = yrow[(size_t)colidx[j] * 4 + q];
    acc8(acc, v);
  }
  float dn = dinv[n];
  int cb = q * 8;
  float4 r0, r1;
  r0.x = fmaxf(fmaf(dn, acc[0], b[cb + 0]), 0.f);
  r0.y = fmaxf(fmaf(dn, acc[1], b[cb + 1]), 0.f);
  r0.z = fmaxf(fmaf(dn, acc[2], b[cb + 2]), 0.f);
  r0.w = fmaxf(fmaf(dn, acc[3], b[cb + 3]), 0.f);
  r1.x = fmaxf(fmaf(dn, acc[4], b[cb + 4]), 0.f);
  r1.y = fmaxf(fmaf(dn, acc[5], b[cb + 5]), 0.f);
  r1.z = fmaxf(fmaf(dn, acc[6], b[cb + 6]), 0.f);
  r1.w = fmaxf(fmaf(dn, acc[7], b[cb + 7]), 0.f);
  ((float4*)out)[(size_t)n * 8 + q * 2 + 0] = r0;
  ((float4*)out)[(size_t)n * 8 + q * 2 + 1] = r1;
}

// ---------------- weight prep: transpose + split to bf16 hi/lo ----------------
__global__ __launch_bounds__(256) void k_prepw(const float* __restrict__ W1,
                                               const float* __restrict__ W2,
                                               unsigned short* __restrict__ Wt1h,
                                               unsigned short* __restrict__ Wt1l,
                                               unsigned short* __restrict__ Wt2h,
                                               unsigned short* __restrict__ Wt2l) {
  int o = blockIdx.x * blockDim.x + threadIdx.x;
  if (o < 256 * 192) {
    int col = o / 192, k = o % 192;
    float v = W1[k * 256 + col];
    unsigned short h = bf16r(v);
    Wt1h[o] = h;
    Wt1l[o] = bf16r(v - bf16f(h));
  } else if (o < 256 * 192 + 256 * 256) {
    int o2 = o - 256 * 192;
    int col = o2 / 256, k = o2 % 256;
    float v = W2[k * 256 + col];
    unsigned short h = bf16r(v);
    Wt2h[o2] = h;
    Wt2l[o2] = bf16r(v - bf16f(h));
  }
}

// ---------------- fused MFMA MLP (R9 numerics, MNODES=80, no-spill bounds) ---
// 80 nodes/block (nt=5), 8 waves x 512 thr (32 outcols/wave). x and W hi/lo
// split; h1 single bf16 plane. smem union 64000 B (static cap 64KB):
//   xs:  xsh [0 .. 32000) B, xsl [32000 .. 64000) B   (dead after layer 1)
//   h1:  [0 .. 42240) B                                (born after barrier)
//   red: [42240 .. 44800) B  — inside dead xsl region, no h1 overlap.
// launch_bounds(512,2): LDS already caps at 2 blocks/CU; (512,4) made the
// allocator pick 64 VGPR and spill 10MB/dispatch (R13-measured).
__device__ __forceinline__ float softplusf(float x) {
  return fmaxf(x, 0.f) + log1pf(expf(-fabsf(x)));
}

#define XS_STRIDE 200   // 192 + 8 pad (bf16 elems)
#define H1_STRIDE 264   // 256 + 8 pad (bf16 elems)
#define MNODES 80

__global__ __launch_bounds__(512, 2) void k_mlp_mfma(
    const float* __restrict__ o1, const float* __restrict__ o2,
    const float* __restrict__ o3, const float* __restrict__ o4,
    const float* __restrict__ o5, const float* __restrict__ st,
    const unsigned short* __restrict__ Wt1h, const unsigned short* __restrict__ Wt1l,
    const float* __restrict__ b1,
    const unsigned short* __restrict__ Wt2h, const unsigned short* __restrict__ Wt2l,
    const float* __restrict__ b2,
    const float* __restrict__ W3, const float* __restrict__ b3,
    float* __restrict__ conc, int N) {
  __shared__ unsigned short smem[2 * MNODES * XS_STRIDE];  // 64000 B union
  unsigned short* xsh = smem;
  unsigned short* xsl = smem + MNODES * XS_STRIDE;
  unsigned short* h1h = smem;                                // aliases xs after barrier
  float* redp = (float*)&smem[MNODES * H1_STRIDE];           // byte 42240, in dead xsl

  const int t = threadIdx.x;
  const int w = t >> 6;          // 0..7
  const int l = t & 63;
  const int l15 = l & 15, lq = l >> 4;
  const int nodeBase = blockIdx.x * MNODES;

  // ---- stage x tile (80 nodes x 192 feats) as bf16 hi/lo into LDS ----
  const float* srcs[6] = {o1, o2, o3, o4, o5, st};
  for (int i = t; i < MNODES * 96; i += 512) {
    int n = i / 96, cp = (i % 96) * 2;
    int gn = nodeBase + n;
    unsigned int pkh = 0, pkl = 0;
    if (gn < N) {
      const float* s = srcs[cp >> 5] + (size_t)gn * 32 + (cp & 31);
      float2 v = *(const float2*)s;
      unsigned short h0 = bf16r(v.x), h1_ = bf16r(v.y);
      unsigned short l0 = bf16r(v.x - bf16f(h0)), l1 = bf16r(v.y - bf16f(h1_));
      pkh = ((unsigned)h1_ << 16) | h0;
      pkl = ((unsigned)l1 << 16) | l0;
    }
    *(unsigned int*)&xsh[n * XS_STRIDE + cp] = pkh;
    *(unsigned int*)&xsl[n * XS_STRIDE + cp] = pkl;
  }
  __syncthreads();

  const int ocBase = w * 32;

  // ---- layer 1: 192 -> 256,  D[outcol][node] ----
  f32x4 acc[2][5];
#pragma unroll
  for (int rt = 0; rt < 2; rt++)
#pragma unroll
    for (int nt = 0; nt < 5; nt++) acc[rt][nt] = (f32x4)0.f;

  for (int kt = 0; kt < 6; kt++) {
    i32x4 ah[2], al[2];
#pragma unroll
    for (int rt = 0; rt < 2; rt++) {
      size_t aoff = (size_t)(ocBase + rt * 16 + l15) * 192 + kt * 32 + lq * 8;
      ah[rt] = *(const i32x4*)&Wt1h[aoff];
      al[rt] = *(const i32x4*)&Wt1l[aoff];
    }
#pragma unroll
    for (int nt = 0; nt < 5; nt++) {
      int boff = (nt * 16 + l15) * XS_STRIDE + kt * 32 + lq * 8;
      i32x4 bh = *(const i32x4*)&xsh[boff];
      i32x4 bl = *(const i32x4*)&xsl[boff];
#pragma unroll
      for (int rt = 0; rt < 2; rt++) mfma16(acc[rt][nt], ah[rt], bh);
#pragma unroll
      for (int rt = 0; rt < 2; rt++) mfma16(acc[rt][nt], al[rt], bh);
#pragma unroll
      for (int rt = 0; rt < 2; rt++) mfma16(acc[rt][nt], ah[rt], bl);
    }
  }
  __syncthreads();  // all xs reads complete before h1 overwrites the union

  // epilogue: +b1, leaky, single bf16 plane, write h1[node][outcol]
#pragma unroll
  for (int rt = 0; rt < 2; rt++) {
    const int oc0 = ocBase + rt * 16 + lq * 4;
    float bb0 = b1[oc0], bb1 = b1[oc0 + 1], bb2 = b1[oc0 + 2], bb3 = b1[oc0 + 3];
#pragma unroll
    for (int nt = 0; nt < 5; nt++) {
      float v0 = acc[rt][nt][0] + bb0; v0 = (v0 > 0.f) ? v0 : 0.01f * v0;
      float v1 = acc[rt][nt][1] + bb1; v1 = (v1 > 0.f) ? v1 : 0.01f * v1;
      float v2 = acc[rt][nt][2] + bb2; v2 = (v2 > 0.f) ? v2 : 0.01f * v2;
      float v3 = acc[rt][nt][3] + bb3; v3 = (v3 > 0.f) ? v3 : 0.01f * v3;
      u32x2 pkh;
      pkh[0] = ((unsigned)bf16r(v1) << 16) | bf16r(v0);
      pkh[1] = ((unsigned)bf16r(v3) << 16) | bf16r(v2);
      int row = nt * 16 + l15;
      *(u32x2*)&h1h[row * H1_STRIDE + oc0] = pkh;
    }
  }
  __syncthreads();

  // ---- layer 2: 256 -> 256 (h1 single-plane: 2 MFMA per rt/nt/kt) ----
  f32x4 acc2[2][5];
#pragma unroll
  for (int rt = 0; rt < 2; rt++)
#pragma unroll
    for (int nt = 0; nt < 5; nt++) acc2[rt][nt] = (f32x4)0.f;

  for (int kt = 0; kt < 8; kt++) {
    i32x4 ah[2], al[2];
#pragma unroll
    for (int rt = 0; rt < 2; rt++) {
      size_t aoff = (size_t)(ocBase + rt * 16 + l15) * 256 + kt * 32 + lq * 8;
      ah[rt] = *(const i32x4*)&Wt2h[aoff];
      al[rt] = *(const i32x4*)&Wt2l[aoff];
    }
#pragma unroll
    for (int nt = 0; nt < 5; nt++) {
      int boff = (nt * 16 + l15) * H1_STRIDE + kt * 32 + lq * 8;
      i32x4 bh = *(const i32x4*)&h1h[boff];
#pragma unroll
      for (int rt = 0; rt < 2; rt++) mfma16(acc2[rt][nt], ah[rt], bh);
#pragma unroll
      for (int rt = 0; rt < 2; rt++) mfma16(acc2[rt][nt], al[rt], bh);
    }
  }
  __syncthreads();  // h1 reads complete block-wide before red (aliased) writes

  // ---- fused: +b2, leaky, dot W3, reduce over outcols ----
#pragma unroll
  for (int nt = 0; nt < 5; nt++) {
    float p = 0.f;
#pragma unroll
    for (int rt = 0; rt < 2; rt++) {
      const int oc0 = ocBase + rt * 16 + lq * 4;
#pragma unroll
      for (int j = 0; j < 4; j++) {
        float v = acc2[rt][nt][j] + b2[oc0 + j];
        v = (v > 0.f) ? v : 0.01f * v;
        p = fmaf(v, W3[oc0 + j], p);
      }
    }
    p += __shfl_xor(p, 16, 64);
    p += __shfl_xor(p, 32, 64);
    if (lq == 0) redp[w * MNODES + nt * 16 + l15] = p;
  }
  __syncthreads();

  if (t < MNODES) {
    int gn = nodeBase + t;
    if (gn < N) {
      float s = redp[0 * MNODES + t] + redp[1 * MNODES + t] + redp[2 * MNODES + t]
              + redp[3 * MNODES + t] + redp[4 * MNODES + t] + redp[5 * MNODES + t]
              + redp[6 * MNODES + t] + redp[7 * MNODES + t] + b3[0];
      conc[gn] = softplusf(s);
    }
  }
}

// ---------------- final normalize ----------------
__global__ __launch_bounds__(256) void k_redsum(const float* __restrict__ conc,
                                                float* __restrict__ total, int N) {
  float s = 0.f;
  for (int i = blockIdx.x * blockDim.x + threadIdx.x; i < N; i += gridDim.x * blockDim.x)
    s += conc[i];
#pragma unroll
  for (int off = 32; off > 0; off >>= 1) s += __shfl_down(s, off, 64);
  __shared__ float ws_[4];
  if ((threadIdx.x & 63) == 0) ws_[threadIdx.x >> 6] = s;
  __syncthreads();
  if (threadIdx.x == 0) atomicAdd(total, ws_[0] + ws_[1] + ws_[2] + ws_[3]);
}

__global__ __launch_bounds__(256) void k_div(const float* __restrict__ conc,
                                             const float* __restrict__ total,
                                             float* __restrict__ out, int N) {
  int i = blockIdx.x * blockDim.x + threadIdx.x;
  if (i < N) out[i] = conc[i] / (total[0] + 1e-20f);
}

extern "C" void kernel_launch(void* const* d_in, const int* in_sizes, int n_in,
                              void* d_out, int out_size, void* d_ws, size_t ws_size,
                              hipStream_t stream) {
  const float* state = (const float*)d_in[0];
  const int*   ei    = (const int*)d_in[1];
  const float* cW1 = (const float*)d_in[2];
  const float* cb1 = (const float*)d_in[3];
  const float* cW2 = (const float*)d_in[4];
  const float* cb2 = (const float*)d_in[5];
  const float* cW3 = (const float*)d_in[6];
  const float* cb3 = (const float*)d_in[7];
  const float* lW1 = (const float*)d_in[8];
  const float* lb1 = (const float*)d_in[9];
  const float* lW2 = (const float*)d_in[10];
  const float* lb2 = (const float*)d_in[11];
  const float* lW3 = (const float*)d_in[12];
  const float* lb3 = (const float*)d_in[13];

  const int N = in_sizes[0] / 32;
  const int E = in_sizes[1] / 2;
  const int* srcI = ei;
  const int* dstI = ei + E;

  char* w = (char*)d_ws;
  size_t off = 0;
  auto alloc = [&](size_t bytes) -> void* {
    void* p = w + off;
    off = (off + bytes + 255) & ~(size_t)255;
    return p;
  };
  int*   cnt       = (int*)alloc((size_t)N * 4);
  int*   cursor    = (int*)alloc((size_t)N * 4);
  float* total     = (float*)alloc(256);
  size_t zbytes = off;  // cnt + cursor + total zeroed together
  int*   rowptr    = (int*)alloc(((size_t)N + 1) * 4);
  int*   blockSums = (int*)alloc(256 * 4);
  int*   colidx    = (int*)alloc((size_t)E * 4);
  float* dinv      = (float*)alloc((size_t)N * 4);
  unsigned short* ybuf = (unsigned short*)alloc((size_t)N * 32 * 2);  // fp16
  float* out1      = (float*)alloc((size_t)N * 32 * 4);
  float* out2      = (float*)alloc((size_t)N * 32 * 4);
  float* out3      = (float*)alloc((size_t)N * 32 * 4);
  float* out4      = (float*)alloc((size_t)N * 32 * 4);
  float* out5      = (float*)alloc((size_t)N * 32 * 4);
  float* conc      = (float*)alloc((size_t)N * 4);
  unsigned short* Wt1h = (unsigned short*)alloc(256 * 192 * 2);
  unsigned short* Wt1l = (unsigned short*)alloc(256 * 192 * 2);
  unsigned short* Wt2h = (unsigned short*)alloc(256 * 256 * 2);
  unsigned short* Wt2l = (unsigned short*)alloc(256 * 256 * 2);

  const int TB = 256;
  hipMemsetAsync(d_ws, 0, zbytes, stream);

  k_count<<<CDIV(E, TB), TB, 0, stream>>>(dstI, cnt, E);
  int NB = CDIV(N, 1024);
  k_scan1<<<NB, TB, 0, stream>>>(cnt, rowptr, blockSums, N);
  k_scan2<<<1, TB, 0, stream>>>(blockSums, NB);
  k_scan3<<<CDIV(N, TB), TB, 0, stream>>>(rowptr, blockSums, N, E);
  k_fill<<<CDIV(E, TB), TB, 0, stream>>>(srcI, dstI, rowptr, cursor, colidx, E);
  k_dinv<<<CDIV(N, TB), TB, 0, stream>>>(cnt, dinv, N);
  k_prepw<<<CDIV(256 * 192 + 256 * 256, TB), TB, 0, stream>>>(lW1, lW2, Wt1h, Wt1l, Wt2h, Wt2l);

  struct Layer { const float* x; const float* W; const float* b; float* out; };
  Layer L[5] = {{state, cW1, cb1, out1},
                {out1,  cW2, cb2, out2},
                {out2,  cW3, cb3, out3},
                {out3,  cW3, cb3, out4},
                {out4,  cW3, cb3, out5}};
  for (int i = 0; i < 5; i++) {
    k_xw<<<CDIV(N * 16, TB), TB, 0, stream>>>(L[i].x, L[i].W, dinv, ybuf, N);
    k_agg<<<CDIV(N, 64), TB, 0, stream>>>(ybuf, rowptr, colidx, dinv, L[i].b, L[i].out, N);
  }

  k_mlp_mfma<<<CDIV(N, MNODES), 512, 0, stream>>>(out1, out2, out3, out4, out5, state,
                                                  Wt1h, Wt1l, lb1, Wt2h, Wt2l, lb2,
                                                  lW3, lb3, conc, N);
  k_redsum<<<256, TB, 0, stream>>>(conc, total, N);
  k_div<<<CDIV(N, TB), TB, 0, stream>>>(conc, total, (float*)d_out, N);
}

// Round 16
// 470.871 us; speedup vs baseline: 1.0320x; 1.0320x over previous
//
#include <hip/hip_runtime.h>
#include <hip/hip_bf16.h>
#include <hip/hip_fp16.h>

#define CDIV(a,b) (((a)+(b)-1)/(b))

typedef float f32x4 __attribute__((ext_vector_type(4)));
typedef int   i32x4 __attribute__((ext_vector_type(4)));
typedef unsigned int u32x2 __attribute__((ext_vector_type(2)));

__device__ __forceinline__ void mfma16(f32x4& d, i32x4 a, i32x4 b) {
  asm("v_mfma_f32_16x16x32_bf16 %0, %1, %2, %0" : "+v"(d) : "v"(a), "v"(b));
}

__device__ __forceinline__ unsigned short bf16r(float x) {
  return __builtin_bit_cast(unsigned short, __float2bfloat16(x));
}
__device__ __forceinline__ float bf16f(unsigned short u) {
  unsigned int w_ = (unsigned int)u << 16;
  return __builtin_bit_cast(float, w_);
}

// NUMERICS LEDGER (measured):
//  - W1/W2 bf16 hi/lo + x hi/lo + h1 single-plane -> absmax 5.96e-8 (floor)
//  - x single-plane -> 2.86e-6 FAIL (R10). Input x MUST stay hi/lo split.
//  - h1 lo-plane dropped -> invisible (R9). Post-layer-1 rounding is cheap.
// PERF LEDGER:
//  - R6/R7: fragment-ordered weight packs failed unexplainably — banned.
//  - R11: degree-sort w/ global atomic cursors = +500us atomics. Banned.
//  - R4/R12: VGPR caps on register-hungry kernels -> silent spill. BUT:
//  - R13 vs R15: k_mlp (512,4)+nt=5 spills ~10MB yet runs 106.8us at occ 37.8;
//    (512,2) removes the spill but drops to 1 block/CU (occ 22) = 122.7us.
//    The spilled 2-block config IS the measured optimum — keep (512,4).
//  - k_mlp lever that works: fewer blocks = less weight refetch
//    (3125->2084->1563->1250 blocks: 205->146->118->107us).

// ---------------- CSR build ----------------
__global__ __launch_bounds__(256) void k_count(const int* __restrict__ dst,
                                               int* __restrict__ cnt, int E) {
  int e = blockIdx.x * blockDim.x + threadIdx.x;
  if (e < E) atomicAdd(&cnt[dst[e]], 1);
}

__global__ __launch_bounds__(256) void k_scan1(const int* __restrict__ cnt,
                                               int* __restrict__ rowptr,
                                               int* __restrict__ blockSums, int N) {
  __shared__ int sdata[256];
  const int t = threadIdx.x;
  const int base = blockIdx.x * 1024;
  int v[4]; int local = 0;
#pragma unroll
  for (int i = 0; i < 4; i++) {
    int idx = base + t * 4 + i;
    v[i] = (idx < N) ? cnt[idx] : 0;
    local += v[i];
  }
  sdata[t] = local;
  __syncthreads();
  for (int off = 1; off < 256; off <<= 1) {
    int x = (t >= off) ? sdata[t - off] : 0;
    __syncthreads();
    sdata[t] += x;
    __syncthreads();
  }
  if (t == 255) blockSums[blockIdx.x] = sdata[255];
  int run = sdata[t] - local;
#pragma unroll
  for (int i = 0; i < 4; i++) {
    int idx = base + t * 4 + i;
    if (idx < N) rowptr[idx] = run;
    run += v[i];
  }
}

__global__ __launch_bounds__(256) void k_scan2(int* blockSums, int NB) {
  __shared__ int sdata[256];
  int t = threadIdx.x;
  int v = (t < NB) ? blockSums[t] : 0;
  sdata[t] = v;
  __syncthreads();
  for (int off = 1; off < 256; off <<= 1) {
    int x = (t >= off) ? sdata[t - off] : 0;
    __syncthreads();
    sdata[t] += x;
    __syncthreads();
  }
  if (t < NB) blockSums[t] = sdata[t] - v;
}

__global__ __launch_bounds__(256) void k_scan3(int* __restrict__ rowptr,
                                               const int* __restrict__ blockSums,
                                               int N, int E) {
  int idx = blockIdx.x * blockDim.x + threadIdx.x;
  if (idx < N) rowptr[idx] += blockSums[idx >> 10];
  if (idx == 0) rowptr[N] = E;
}

__global__ __launch_bounds__(256) void k_fill(const int* __restrict__ src,
                                              const int* __restrict__ dst,
                                              const int* __restrict__ rowptr,
                                              int* __restrict__ cursor,
                                              int* __restrict__ colidx, int E) {
  int e = blockIdx.x * blockDim.x + threadIdx.x;
  if (e < E) {
    int d = dst[e];
    int pos = rowptr[d] + atomicAdd(&cursor[d], 1);
    colidx[pos] = src[e];
  }
}

__global__ __launch_bounds__(256) void k_dinv(const int* __restrict__ cnt,
                                              float* __restrict__ dinv, int N) {
  int i = blockIdx.x * blockDim.x + threadIdx.x;
  if (i < N) dinv[i] = rsqrtf((float)cnt[i] + 1.0f);
}

// ---------------- GCN layer ----------------
// y[n][c] = half( dinv[n] * sum_k x[n][k] * W[k][c] )   (fp16 table, 64 B/row)
__global__ __launch_bounds__(256) void k_xw(const float* __restrict__ x,
                                            const float* __restrict__ W,
                                            const float* __restrict__ dinv,
                                            unsigned short* __restrict__ y, int N) {
  __shared__ float Ws[1024];
  int t = threadIdx.x;
#pragma unroll
  for (int i = 0; i < 4; i++) Ws[t + i * 256] = W[t + i * 256];
  __syncthreads();
  int gid = blockIdx.x * blockDim.x + t;
  int n = gid >> 4, c = (gid & 15) * 2;
  if (n < N) {
    const float4* xr4 = (const float4*)(x + (size_t)n * 32);
    float a0 = 0.f, a1 = 0.f;
#pragma unroll
    for (int k4 = 0; k4 < 8; k4++) {
      float4 xv = xr4[k4];
      int k = k4 * 4;
      a0 = fmaf(xv.x, Ws[(k + 0) * 32 + c], a0); a1 = fmaf(xv.x, Ws[(k + 0) * 32 + c + 1], a1);
      a0 = fmaf(xv.y, Ws[(k + 1) * 32 + c], a0); a1 = fmaf(xv.y, Ws[(k + 1) * 32 + c + 1], a1);
      a0 = fmaf(xv.z, Ws[(k + 2) * 32 + c], a0); a1 = fmaf(xv.z, Ws[(k + 2) * 32 + c + 1], a1);
      a0 = fmaf(xv.w, Ws[(k + 3) * 32 + c], a0); a1 = fmaf(xv.w, Ws[(k + 3) * 32 + c + 1], a1);
    }
    float dn = dinv[n];
    __half2 h = __floats2half2_rn(a0 * dn, a1 * dn);
    *(__half2*)&y[(size_t)gid * 2] = h;
  }
}

__device__ __forceinline__ void acc8(float* acc, uint4 v) {
  float2 f;
  f = __half22float2(__builtin_bit_cast(__half2, v.x)); acc[0] += f.x; acc[1] += f.y;
  f = __half22float2(__builtin_bit_cast(__half2, v.y)); acc[2] += f.x; acc[3] += f.y;
  f = __half22float2(__builtin_bit_cast(__half2, v.z)); acc[4] += f.x; acc[5] += f.y;
  f = __half22float2(__builtin_bit_cast(__half2, v.w)); acc[6] += f.x; acc[7] += f.y;
}

// out[n] = relu(dinv[n]*(sum_{s in N(n)} y[s] + y[n]) + b)
// R10-proven exact config: 4 lanes/node, 16/8/4/scalar unroll tails,
// DEFAULT launch bounds (VGPR ~100 — capping spills, see ledger).
__global__ __launch_bounds__(256) void k_agg(const unsigned short* __restrict__ y,
                                             const int* __restrict__ rowptr,
                                             const int* __restrict__ colidx,
                                             const float* __restrict__ dinv,
                                             const float* __restrict__ b,
                                             float* __restrict__ out, int N) {
  int t = threadIdx.x;
  int q = t & 3;
  int n = blockIdx.x * 64 + (t >> 2);
  if (n >= N) return;
  const uint4* yrow = (const uint4*)y;
  float acc[8];
  {
    uint4 v = yrow[(size_t)n * 4 + q];  // self-loop term
    float2 f;
    f = __half22float2(__builtin_bit_cast(__half2, v.x)); acc[0] = f.x; acc[1] = f.y;
    f = __half22float2(__builtin_bit_cast(__half2, v.y)); acc[2] = f.x; acc[3] = f.y;
    f = __half22float2(__builtin_bit_cast(__half2, v.z)); acc[4] = f.x; acc[5] = f.y;
    f = __half22float2(__builtin_bit_cast(__half2, v.w)); acc[6] = f.x; acc[7] = f.y;
  }
  int beg = rowptr[n], end = rowptr[n + 1];
  int j = beg;
  for (; j + 16 <= end; j += 16) {
    uint4 v[16];
#pragma unroll
    for (int u = 0; u < 16; u++) v[u] = yrow[(size_t)colidx[j + u] * 4 + q];
#pragma unroll
    for (int u = 0; u < 16; u++) acc8(acc, v[u]);
  }
  for (; j + 8 <= end; j += 8) {
    uint4 v[8];
#pragma unroll
    for (int u = 0; u < 8; u++) v[u] = yrow[(size_t)colidx[j + u] * 4 + q];
#pragma unroll
    for (int u = 0; u < 8; u++) acc8(acc, v[u]);
  }
  for (; j + 4 <= end; j += 4) {
    uint4 v[4];
#pragma unroll
    for (int u = 0; u < 4; u++) v[u] = yrow[(size_t)colidx[j + u] * 4 + q];
#pragma unroll
    for (int u = 0; u < 4; u++) acc8(acc, v[u]);
  }
  for (; j < end; j++) {
    uint4 v = yrow[(size_t)colidx[j] * 4 + q];
    acc8(acc, v);
  }
  float dn = dinv[n];
  int cb = q * 8;
  float4 r0, r1;
  r0.x = fmaxf(fmaf(dn, acc[0], b[cb + 0]), 0.f);
  r0.y = fmaxf(fmaf(dn, acc[1], b[cb + 1]), 0.f);
  r0.z = fmaxf(fmaf(dn, acc[2], b[cb + 2]), 0.f);
  r0.w = fmaxf(fmaf(dn, acc[3], b[cb + 3]), 0.f);
  r1.x = fmaxf(fmaf(dn, acc[4], b[cb + 4]), 0.f);
  r1.y = fmaxf(fmaf(dn, acc[5], b[cb + 5]), 0.f);
  r1.z = fmaxf(fmaf(dn, acc[6], b[cb + 6]), 0.f);
  r1.w = fmaxf(fmaf(dn, acc[7], b[cb + 7]), 0.f);
  ((float4*)out)[(size_t)n * 8 + q * 2 + 0] = r0;
  ((float4*)out)[(size_t)n * 8 + q * 2 + 1] = r1;
}

// ---------------- weight prep: transpose + split to bf16 hi/lo ----------------
__global__ __launch_bounds__(256) void k_prepw(const float* __restrict__ W1,
                                               const float* __restrict__ W2,
                                               unsigned short* __restrict__ Wt1h,
                                               unsigned short* __restrict__ Wt1l,
                                               unsigned short* __restrict__ Wt2h,
                                               unsigned short* __restrict__ Wt2l) {
  int o = blockIdx.x * blockDim.x + threadIdx.x;
  if (o < 256 * 192) {
    int col = o / 192, k = o % 192;
    float v = W1[k * 256 + col];
    unsigned short h = bf16r(v);
    Wt1h[o] = h;
    Wt1l[o] = bf16r(v - bf16f(h));
  } else if (o < 256 * 192 + 256 * 256) {
    int o2 = o - 256 * 192;
    int col = o2 / 256, k = o2 % 256;
    float v = W2[k * 256 + col];
    unsigned short h = bf16r(v);
    Wt2h[o2] = h;
    Wt2l[o2] = bf16r(v - bf16f(h));
  }
}

// ---------------- fused MFMA MLP (R13-exact: measured optimum 106.8us) -------
// 80 nodes/block (nt=5), 8 waves x 512 thr (32 outcols/wave). x and W hi/lo
// split; h1 single bf16 plane. smem union 64000 B:
//   xs:  xsh [0 .. 32000) B, xsl [32000 .. 64000) B   (dead after layer 1)
//   h1:  [0 .. 42240) B                                (born after barrier)
//   red: [42240 .. 44800) B  — inside dead xsl region, no h1 overlap.
// launch_bounds(512,4): yes this spills ~10MB/dispatch (VGPR 64), but it keeps
// 2 blocks/CU resident (occ 37.8) and measures 106.8us; the no-spill (512,2)
// variant drops to 1 block/CU (occ 22) and measures 122.7us. Spilled wins.
__device__ __forceinline__ float softplusf(float x) {
  return fmaxf(x, 0.f) + log1pf(expf(-fabsf(x)));
}

#define XS_STRIDE 200   // 192 + 8 pad (bf16 elems)
#define H1_STRIDE 264   // 256 + 8 pad (bf16 elems)
#define MNODES 80

__global__ __launch_bounds__(512, 4) void k_mlp_mfma(
    const float* __restrict__ o1, const float* __restrict__ o2,
    const float* __restrict__ o3, const float* __restrict__ o4,
    const float* __restrict__ o5, const float* __restrict__ st,
    const unsigned short* __restrict__ Wt1h, const unsigned short* __restrict__ Wt1l,
    const float* __restrict__ b1,
    const unsigned short* __restrict__ Wt2h, const unsigned short* __restrict__ Wt2l,
    const float* __restrict__ b2,
    const float* __restrict__ W3, const float* __restrict__ b3,
    float* __restrict__ conc, int N) {
  __shared__ unsigned short smem[2 * MNODES * XS_STRIDE];  // 64000 B union
  unsigned short* xsh = smem;
  unsigned short* xsl = smem + MNODES * XS_STRIDE;
  unsigned short* h1h = smem;                                // aliases xs after barrier
  float* redp = (float*)&smem[MNODES * H1_STRIDE];           // byte 42240, in dead xsl

  const int t = threadIdx.x;
  const int w = t >> 6;          // 0..7
  const int l = t & 63;
  const int l15 = l & 15, lq = l >> 4;
  const int nodeBase = blockIdx.x * MNODES;

  // ---- stage x tile (80 nodes x 192 feats) as bf16 hi/lo into LDS ----
  const float* srcs[6] = {o1, o2, o3, o4, o5, st};
  for (int i = t; i < MNODES * 96; i += 512) {
    int n = i / 96, cp = (i % 96) * 2;
    int gn = nodeBase + n;
    unsigned int pkh = 0, pkl = 0;
    if (gn < N) {
      const float* s = srcs[cp >> 5] + (size_t)gn * 32 + (cp & 31);
      float2 v = *(const float2*)s;
      unsigned short h0 = bf16r(v.x), h1_ = bf16r(v.y);
      unsigned short l0 = bf16r(v.x - bf16f(h0)), l1 = bf16r(v.y - bf16f(h1_));
      pkh = ((unsigned)h1_ << 16) | h0;
      pkl = ((unsigned)l1 << 16) | l0;
    }
    *(unsigned int*)&xsh[n * XS_STRIDE + cp] = pkh;
    *(unsigned int*)&xsl[n * XS_STRIDE + cp] = pkl;
  }
  __syncthreads();

  const int ocBase = w * 32;

  // ---- layer 1: 192 -> 256,  D[outcol][node] ----
  f32x4 acc[2][5];
#pragma unroll
  for (int rt = 0; rt < 2; rt++)
#pragma unroll
    for (int nt = 0; nt < 5; nt++) acc[rt][nt] = (f32x4)0.f;

  for (int kt = 0; kt < 6; kt++) {
    i32x4 ah[2], al[2];
#pragma unroll
    for (int rt = 0; rt < 2; rt++) {
      size_t aoff = (size_t)(ocBase + rt * 16 + l15) * 192 + kt * 32 + lq * 8;
      ah[rt] = *(const i32x4*)&Wt1h[aoff];
      al[rt] = *(const i32x4*)&Wt1l[aoff];
    }
#pragma unroll
    for (int nt = 0; nt < 5; nt++) {
      int boff = (nt * 16 + l15) * XS_STRIDE + kt * 32 + lq * 8;
      i32x4 bh = *(const i32x4*)&xsh[boff];
      i32x4 bl = *(const i32x4*)&xsl[boff];
#pragma unroll
      for (int rt = 0; rt < 2; rt++) mfma16(acc[rt][nt], ah[rt], bh);
#pragma unroll
      for (int rt = 0; rt < 2; rt++) mfma16(acc[rt][nt], al[rt], bh);
#pragma unroll
      for (int rt = 0; rt < 2; rt++) mfma16(acc[rt][nt], ah[rt], bl);
    }
  }
  __syncthreads();  // all xs reads complete before h1 overwrites the union

  // epilogue: +b1, leaky, single bf16 plane, write h1[node][outcol]
#pragma unroll
  for (int rt = 0; rt < 2; rt++) {
    const int oc0 = ocBase + rt * 16 + lq * 4;
    float bb0 = b1[oc0], bb1 = b1[oc0 + 1], bb2 = b1[oc0 + 2], bb3 = b1[oc0 + 3];
#pragma unroll
    for (int nt = 0; nt < 5; nt++) {
      float v0 = acc[rt][nt][0] + bb0; v0 = (v0 > 0.f) ? v0 : 0.01f * v0;
      float v1 = acc[rt][nt][1] + bb1; v1 = (v1 > 0.f) ? v1 : 0.01f * v1;
      float v2 = acc[rt][nt][2] + bb2; v2 = (v2 > 0.f) ? v2 : 0.01f * v2;
      float v3 = acc[rt][nt][3] + bb3; v3 = (v3 > 0.f) ? v3 : 0.01f * v3;
      u32x2 pkh;
      pkh[0] = ((unsigned)bf16r(v1) << 16) | bf16r(v0);
      pkh[1] = ((unsigned)bf16r(v3) << 16) | bf16r(v2);
      int row = nt * 16 + l15;
      *(u32x2*)&h1h[row * H1_STRIDE + oc0] = pkh;
    }
  }
  __syncthreads();

  // ---- layer 2: 256 -> 256 (h1 single-plane: 2 MFMA per rt/nt/kt) ----
  f32x4 acc2[2][5];
#pragma unroll
  for (int rt = 0; rt < 2; rt++)
#pragma unroll
    for (int nt = 0; nt < 5; nt++) acc2[rt][nt] = (f32x4)0.f;

  for (int kt = 0; kt < 8; kt++) {
    i32x4 ah[2], al[2];
#pragma unroll
    for (int rt = 0; rt < 2; rt++) {
      size_t aoff = (size_t)(ocBase + rt * 16 + l15) * 256 + kt * 32 + lq * 8;
      ah[rt] = *(const i32x4*)&Wt2h[aoff];
      al[rt] = *(const i32x4*)&Wt2l[aoff];
    }
#pragma unroll
    for (int nt = 0; nt < 5; nt++) {
      int boff = (nt * 16 + l15) * H1_STRIDE + kt * 32 + lq * 8;
      i32x4 bh = *(const i32x4*)&h1h[boff];
#pragma unroll
      for (int rt = 0; rt < 2; rt++) mfma16(acc2[rt][nt], ah[rt], bh);
#pragma unroll
      for (int rt = 0; rt < 2; rt++) mfma16(acc2[rt][nt], al[rt], bh);
    }
  }
  __syncthreads();  // h1 reads complete block-wide before red (aliased) writes

  // ---- fused: +b2, leaky, dot W3, reduce over outcols ----
#pragma unroll
  for (int nt = 0; nt < 5; nt++) {
    float p = 0.f;
#pragma unroll
    for (int rt = 0; rt < 2; rt++) {
      const int oc0 = ocBase + rt * 16 + lq * 4;
#pragma unroll
      for (int j = 0; j < 4; j++) {
        float v = acc2[rt][nt][j] + b2[oc0 + j];
        v = (v > 0.f) ? v : 0.01f * v;
        p = fmaf(v, W3[oc0 + j], p);
      }
    }
    p += __shfl_xor(p, 16, 64);
    p += __shfl_xor(p, 32, 64);
    if (lq == 0) redp[w * MNODES + nt * 16 + l15] = p;
  }
  __syncthreads();

  if (t < MNODES) {
    int gn = nodeBase + t;
    if (gn < N) {
      float s = redp[0 * MNODES + t] + redp[1 * MNODES + t] + redp[2 * MNODES + t]
              + redp[3 * MNODES + t] + redp[4 * MNODES + t] + redp[5 * MNODES + t]
              + redp[6 * MNODES + t] + redp[7 * MNODES + t] + b3[0];
      conc[gn] = softplusf(s);
    }
  }
}

// ---------------- final normalize ----------------
__global__ __launch_bounds__(256) void k_redsum(const float* __restrict__ conc,
                                                float* __restrict__ total, int N) {
  float s = 0.f;
  for (int i = blockIdx.x * blockDim.x + threadIdx.x; i < N; i += gridDim.x * blockDim.x)
    s += conc[i];
#pragma unroll
  for (int off = 32; off > 0; off >>= 1) s += __shfl_down(s, off, 64);
  __shared__ float ws_[4];
  if ((threadIdx.x & 63) == 0) ws_[threadIdx.x >> 6] = s;
  __syncthreads();
  if (threadIdx.x == 0) atomicAdd(total, ws_[0] + ws_[1] + ws_[2] + ws_[3]);
}

__global__ __launch_bounds__(256) void k_div(const float* __restrict__ conc,
                                             const float* __restrict__ total,
                                             float* __restrict__ out, int N) {
  int i = blockIdx.x * blockDim.x + threadIdx.x;
  if (i < N) out[i] = conc[i] / (total[0] + 1e-20f);
}

extern "C" void kernel_launch(void* const* d_in, const int* in_sizes, int n_in,
                              void* d_out, int out_size, void* d_ws, size_t ws_size,
                              hipStream_t stream) {
  const float* state = (const float*)d_in[0];
  const int*   ei    = (const int*)d_in[1];
  const float* cW1 = (const float*)d_in[2];
  const float* cb1 = (const float*)d_in[3];
  const float* cW2 = (const float*)d_in[4];
  const float* cb2 = (const float*)d_in[5];
  const float* cW3 = (const float*)d_in[6];
  const float* cb3 = (const float*)d_in[7];
  const float* lW1 = (const float*)d_in[8];
  const float* lb1 = (const float*)d_in[9];
  const float* lW2 = (const float*)d_in[10];
  const float* lb2 = (const float*)d_in[11];
  const float* lW3 = (const float*)d_in[12];
  const float* lb3 = (const float*)d_in[13];

  const int N = in_sizes[0] / 32;
  const int E = in_sizes[1] / 2;
  const int* srcI = ei;
  const int* dstI = ei + E;

  char* w = (char*)d_ws;
  size_t off = 0;
  auto alloc = [&](size_t bytes) -> void* {
    void* p = w + off;
    off = (off + bytes + 255) & ~(size_t)255;
    return p;
  };
  int*   cnt       = (int*)alloc((size_t)N * 4);
  int*   cursor    = (int*)alloc((size_t)N * 4);
  float* total     = (float*)alloc(256);
  size_t zbytes = off;  // cnt + cursor + total zeroed together
  int*   rowptr    = (int*)alloc(((size_t)N + 1) * 4);
  int*   blockSums = (int*)alloc(256 * 4);
  int*   colidx    = (int*)alloc((size_t)E * 4);
  float* dinv      = (float*)alloc((size_t)N * 4);
  unsigned short* ybuf = (unsigned short*)alloc((size_t)N * 32 * 2);  // fp16
  float* out1      = (float*)alloc((size_t)N * 32 * 4);
  float* out2      = (float*)alloc((size_t)N * 32 * 4);
  float* out3      = (float*)alloc((size_t)N * 32 * 4);
  float* out4      = (float*)alloc((size_t)N * 32 * 4);
  float* out5      = (float*)alloc((size_t)N * 32 * 4);
  float* conc      = (float*)alloc((size_t)N * 4);
  unsigned short* Wt1h = (unsigned short*)alloc(256 * 192 * 2);
  unsigned short* Wt1l = (unsigned short*)alloc(256 * 192 * 2);
  unsigned short* Wt2h = (unsigned short*)alloc(256 * 256 * 2);
  unsigned short* Wt2l = (unsigned short*)alloc(256 * 256 * 2);

  const int TB = 256;
  hipMemsetAsync(d_ws, 0, zbytes, stream);

  k_count<<<CDIV(E, TB), TB, 0, stream>>>(dstI, cnt, E);
  int NB = CDIV(N, 1024);
  k_scan1<<<NB, TB, 0, stream>>>(cnt, rowptr, blockSums, N);
  k_scan2<<<1, TB, 0, stream>>>(blockSums, NB);
  k_scan3<<<CDIV(N, TB), TB, 0, stream>>>(rowptr, blockSums, N, E);
  k_fill<<<CDIV(E, TB), TB, 0, stream>>>(srcI, dstI, rowptr, cursor, colidx, E);
  k_dinv<<<CDIV(N, TB), TB, 0, stream>>>(cnt, dinv, N);
  k_prepw<<<CDIV(256 * 192 + 256 * 256, TB), TB, 0, stream>>>(lW1, lW2, Wt1h, Wt1l, Wt2h, Wt2l);

  struct Layer { const float* x; const float* W; const float* b; float* out; };
  Layer L[5] = {{state, cW1, cb1, out1},
                {out1,  cW2, cb2, out2},
                {out2,  cW3, cb3, out3},
                {out3,  cW3, cb3, out4},
                {out4,  cW3, cb3, out5}};
  for (int i = 0; i < 5; i++) {
    k_xw<<<CDIV(N * 16, TB), TB, 0, stream>>>(L[i].x, L[i].W, dinv, ybuf, N);
    k_agg<<<CDIV(N, 64), TB, 0, stream>>>(ybuf, rowptr, colidx, dinv, L[i].b, L[i].out, N);
  }

  k_mlp_mfma<<<CDIV(N, MNODES), 512, 0, stream>>>(out1, out2, out3, out4, out5, state,
                                                  Wt1h, Wt1l, lb1, Wt2h, Wt2l, lb2,
                                                  lW3, lb3, conc, N);
  k_redsum<<<256, TB, 0, stream>>>(conc, total, N);
  k_div<<<CDIV(N, TB), TB, 0, stream>>>(conc, total, (float*)d_out, N);
}

// Round 17
// 411.825 us; speedup vs baseline: 1.1799x; 1.1434x over previous
//
#include <hip/hip_runtime.h>
#include <hip/hip_bf16.h>
#include <hip/hip_fp16.h>

#define CDIV(a,b) (((a)+(b)-1)/(b))

typedef float f32x4 __attribute__((ext_vector_type(4)));
typedef int   i32x4 __attribute__((ext_vector_type(4)));
typedef unsigned int u32x2 __attribute__((ext_vector_type(2)));

__device__ __forceinline__ void mfma16(f32x4& d, i32x4 a, i32x4 b) {
  asm("v_mfma_f32_16x16x32_bf16 %0, %1, %2, %0" : "+v"(d) : "v"(a), "v"(b));
}

__device__ __forceinline__ unsigned short bf16r(float x) {
  return __builtin_bit_cast(unsigned short, __float2bfloat16(x));
}
__device__ __forceinline__ float bf16f(unsigned short u) {
  unsigned int w_ = (unsigned int)u << 16;
  return __builtin_bit_cast(float, w_);
}

// NUMERICS LEDGER (measured):
//  - W1/W2 bf16 hi/lo + x hi/lo + h1 single-plane -> absmax 5.96e-8 (floor)
//  - x single-plane -> 2.86e-6 FAIL (R10). Input x MUST stay hi/lo split.
//  - h1 lo-plane dropped -> invisible (R9).
// PERF LEDGER:
//  - R6/R7 weight packs banned; R11 global-atomic-cursor sort banned.
//  - R13 vs R15: k_mlp (512,4)+spill = 106.8us BEATS (512,2) no-spill 122.7us
//    (occupancy 2 blocks/CU > spill cost). Keep (512,4).
//  - R16: k_fill was 115us: 4B scattered colidx stores -> 107MB of 64B
//    line-writebacks (cross-XCD churn). Replaced by bucketed 2-level CSR:
//    LDS scatter + coalesced global writes, deterministic bases (no global
//    atomic cursors per R11).

#define BUCK_SHIFT 7
#define BUCK_W     128
#define MAXBUCK    1024     // LDS arrays sized for <=1024 buckets (N<=131072)
#define NBLK1      256
#define P2CAP      4096     // bucket edge capacity (mean~2046, sigma~45)

// ---------------- CSR build ----------------
__global__ __launch_bounds__(256) void k_count(const int* __restrict__ dst,
                                               int* __restrict__ cnt, int E) {
  int e = blockIdx.x * blockDim.x + threadIdx.x;
  if (e < E) atomicAdd(&cnt[dst[e]], 1);
}

__global__ __launch_bounds__(256) void k_scan1(const int* __restrict__ cnt,
                                               int* __restrict__ rowptr,
                                               int* __restrict__ blockSums, int N) {
  __shared__ int sdata[256];
  const int t = threadIdx.x;
  const int base = blockIdx.x * 1024;
  int v[4]; int local = 0;
#pragma unroll
  for (int i = 0; i < 4; i++) {
    int idx = base + t * 4 + i;
    v[i] = (idx < N) ? cnt[idx] : 0;
    local += v[i];
  }
  sdata[t] = local;
  __syncthreads();
  for (int off = 1; off < 256; off <<= 1) {
    int x = (t >= off) ? sdata[t - off] : 0;
    __syncthreads();
    sdata[t] += x;
    __syncthreads();
  }
  if (t == 255) blockSums[blockIdx.x] = sdata[255];
  int run = sdata[t] - local;
#pragma unroll
  for (int i = 0; i < 4; i++) {
    int idx = base + t * 4 + i;
    if (idx < N) rowptr[idx] = run;
    run += v[i];
  }
}

__global__ __launch_bounds__(256) void k_scan2(int* blockSums, int NB) {
  __shared__ int sdata[256];
  int t = threadIdx.x;
  int v = (t < NB) ? blockSums[t] : 0;
  sdata[t] = v;
  __syncthreads();
  for (int off = 1; off < 256; off <<= 1) {
    int x = (t >= off) ? sdata[t - off] : 0;
    __syncthreads();
    sdata[t] += x;
    __syncthreads();
  }
  if (t < NB) blockSums[t] = sdata[t] - v;
}

__global__ __launch_bounds__(256) void k_scan3(int* __restrict__ rowptr,
                                               const int* __restrict__ blockSums,
                                               int N, int E) {
  int idx = blockIdx.x * blockDim.x + threadIdx.x;
  if (idx < N) rowptr[idx] += blockSums[idx >> 10];
  if (idx == 0) rowptr[N] = E;
}

__global__ __launch_bounds__(256) void k_dinv(const int* __restrict__ cnt,
                                              float* __restrict__ dinv, int N) {
  int i = blockIdx.x * blockDim.x + threadIdx.x;
  if (i < N) dinv[i] = rsqrtf((float)cnt[i] + 1.0f);
}

// --- bucketed edge transpose: hist[blk][b] (coalesced write per block) ---
__global__ __launch_bounds__(256) void k_p1hist(const int* __restrict__ dst,
                                                int* __restrict__ hist,
                                                int E, int nbuck, int chunk) {
  __shared__ int h[MAXBUCK];
  const int t = threadIdx.x, blk = blockIdx.x;
  for (int i = t; i < MAXBUCK; i += 256) h[i] = 0;
  __syncthreads();
  int e0 = blk * chunk, e1 = min(e0 + chunk, E);
  for (int e = e0 + t; e < e1; e += 256) atomicAdd(&h[dst[e] >> BUCK_SHIFT], 1);
  __syncthreads();
  for (int b = t; b < nbuck; b += 256) hist[blk * nbuck + b] = h[b];
}

// per-bucket exclusive scan over 256 block-counts -> base[b][blk], btotal[b]
__global__ __launch_bounds__(256) void k_pscan(const int* __restrict__ hist,
                                               int* __restrict__ base,
                                               int* __restrict__ btotal, int nbuck) {
  __shared__ int s[256];
  const int b = blockIdx.x, t = threadIdx.x;
  int v = hist[t * nbuck + b];
  s[t] = v;
  __syncthreads();
  for (int off = 1; off < 256; off <<= 1) {
    int x = (t >= off) ? s[t - off] : 0;
    __syncthreads();
    s[t] += x;
    __syncthreads();
  }
  base[b * 256 + t] = s[t] - v;  // exclusive
  if (t == 255) btotal[b] = s[255];
}

// exclusive scan over bucket totals -> bbase[0..nbuck], bbase[nbuck]=E
__global__ __launch_bounds__(1024) void k_pscan2(const int* __restrict__ btotal,
                                                 int* __restrict__ bbase,
                                                 int nbuck, int E) {
  __shared__ int s[1024];
  int t = threadIdx.x;
  int v = (t < nbuck) ? btotal[t] : 0;
  s[t] = v;
  __syncthreads();
  for (int off = 1; off < 1024; off <<= 1) {
    int x = (t >= off) ? s[t - off] : 0;
    __syncthreads();
    s[t] += x;
    __syncthreads();
  }
  if (t < nbuck) bbase[t] = s[t] - v;
  if (t == 0) bbase[nbuck] = E;
}

// scatter (src,dst) pairs into bucket-grouped array (LDS cursors only)
__global__ __launch_bounds__(256) void k_p1scatter(const int* __restrict__ src,
                                                   const int* __restrict__ dst,
                                                   const int* __restrict__ base,
                                                   const int* __restrict__ bbase,
                                                   int2* __restrict__ bkt,
                                                   int E, int nbuck, int chunk) {
  __shared__ int cur[MAXBUCK];
  const int t = threadIdx.x, blk = blockIdx.x;
  for (int i = t; i < MAXBUCK; i += 256) cur[i] = 0;
  __syncthreads();
  int e0 = blk * chunk, e1 = min(e0 + chunk, E);
  for (int e = e0 + t; e < e1; e += 256) {
    int d = dst[e];
    int b = d >> BUCK_SHIFT;
    int loc = atomicAdd(&cur[b], 1);
    int pos = bbase[b] + base[b * 256 + blk] + loc;
    bkt[pos] = make_int2(src[e], d);
  }
}

// per-bucket CSR segment build in LDS, coalesced colidx write
__global__ __launch_bounds__(256) void k_p2build(const int2* __restrict__ bkt,
                                                 const int* __restrict__ bbase,
                                                 const int* __restrict__ rowptr,
                                                 int* __restrict__ colidx, int N) {
  __shared__ int cur[BUCK_W];
  __shared__ int col[P2CAP];
  const int b = blockIdx.x, t = threadIdx.x;
  const int lo = b << BUCK_SHIFT;
  for (int i = t; i < BUCK_W; i += 256) cur[i] = 0;
  __syncthreads();
  const int e0 = bbase[b], m = bbase[b + 1] - e0;
  const int rowbase = rowptr[lo];
  for (int i = t; i < m; i += 256) {
    int2 p = bkt[e0 + i];
    int off = rowptr[p.y] - rowbase + atomicAdd(&cur[p.y - lo], 1);
    if (off < P2CAP) col[off] = p.x;
  }
  __syncthreads();
  for (int i = t; i < m; i += 256) colidx[rowbase + i] = col[i];
}

// ---------------- GCN layer ----------------
__global__ __launch_bounds__(256) void k_xw(const float* __restrict__ x,
                                            const float* __restrict__ W,
                                            const float* __restrict__ dinv,
                                            unsigned short* __restrict__ y, int N) {
  __shared__ float Ws[1024];
  int t = threadIdx.x;
#pragma unroll
  for (int i = 0; i < 4; i++) Ws[t + i * 256] = W[t + i * 256];
  __syncthreads();
  int gid = blockIdx.x * blockDim.x + t;
  int n = gid >> 4, c = (gid & 15) * 2;
  if (n < N) {
    const float4* xr4 = (const float4*)(x + (size_t)n * 32);
    float a0 = 0.f, a1 = 0.f;
#pragma unroll
    for (int k4 = 0; k4 < 8; k4++) {
      float4 xv = xr4[k4];
      int k = k4 * 4;
      a0 = fmaf(xv.x, Ws[(k + 0) * 32 + c], a0); a1 = fmaf(xv.x, Ws[(k + 0) * 32 + c + 1], a1);
      a0 = fmaf(xv.y, Ws[(k + 1) * 32 + c], a0); a1 = fmaf(xv.y, Ws[(k + 1) * 32 + c + 1], a1);
      a0 = fmaf(xv.z, Ws[(k + 2) * 32 + c], a0); a1 = fmaf(xv.z, Ws[(k + 2) * 32 + c + 1], a1);
      a0 = fmaf(xv.w, Ws[(k + 3) * 32 + c], a0); a1 = fmaf(xv.w, Ws[(k + 3) * 32 + c + 1], a1);
    }
    float dn = dinv[n];
    __half2 h = __floats2half2_rn(a0 * dn, a1 * dn);
    *(__half2*)&y[(size_t)gid * 2] = h;
  }
}

__device__ __forceinline__ void acc8(float* acc, uint4 v) {
  float2 f;
  f = __half22float2(__builtin_bit_cast(__half2, v.x)); acc[0] += f.x; acc[1] += f.y;
  f = __half22float2(__builtin_bit_cast(__half2, v.y)); acc[2] += f.x; acc[3] += f.y;
  f = __half22float2(__builtin_bit_cast(__half2, v.z)); acc[4] += f.x; acc[5] += f.y;
  f = __half22float2(__builtin_bit_cast(__half2, v.w)); acc[6] += f.x; acc[7] += f.y;
}

// R10-proven: 4 lanes/node, 16/8/4/scalar tails, DEFAULT bounds.
__global__ __launch_bounds__(256) void k_agg(const unsigned short* __restrict__ y,
                                             const int* __restrict__ rowptr,
                                             const int* __restrict__ colidx,
                                             const float* __restrict__ dinv,
                                             const float* __restrict__ b,
                                             float* __restrict__ out, int N) {
  int t = threadIdx.x;
  int q = t & 3;
  int n = blockIdx.x * 64 + (t >> 2);
  if (n >= N) return;
  const uint4* yrow = (const uint4*)y;
  float acc[8];
  {
    uint4 v = yrow[(size_t)n * 4 + q];
    float2 f;
    f = __half22float2(__builtin_bit_cast(__half2, v.x)); acc[0] = f.x; acc[1] = f.y;
    f = __half22float2(__builtin_bit_cast(__half2, v.y)); acc[2] = f.x; acc[3] = f.y;
    f = __half22float2(__builtin_bit_cast(__half2, v.z)); acc[4] = f.x; acc[5] = f.y;
    f = __half22float2(__builtin_bit_cast(__half2, v.w)); acc[6] = f.x; acc[7] = f.y;
  }
  int beg = rowptr[n], end = rowptr[n + 1];
  int j = beg;
  for (; j + 16 <= end; j += 16) {
    uint4 v[16];
#pragma unroll
    for (int u = 0; u < 16; u++) v[u] = yrow[(size_t)colidx[j + u] * 4 + q];
#pragma unroll
    for (int u = 0; u < 16; u++) acc8(acc, v[u]);
  }
  for (; j + 8 <= end; j += 8) {
    uint4 v[8];
#pragma unroll
    for (int u = 0; u < 8; u++) v[u] = yrow[(size_t)colidx[j + u] * 4 + q];
#pragma unroll
    for (int u = 0; u < 8; u++) acc8(acc, v[u]);
  }
  for (; j + 4 <= end; j += 4) {
    uint4 v[4];
#pragma unroll
    for (int u = 0; u < 4; u++) v[u] = yrow[(size_t)colidx[j + u] * 4 + q];
#pragma unroll
    for (int u = 0; u < 4; u++) acc8(acc, v[u]);
  }
  for (; j < end; j++) {
    uint4 v = yrow[(size_t)colidx[j] * 4 + q];
    acc8(acc, v);
  }
  float dn = dinv[n];
  int cb = q * 8;
  float4 r0, r1;
  r0.x = fmaxf(fmaf(dn, acc[0], b[cb + 0]), 0.f);
  r0.y = fmaxf(fmaf(dn, acc[1], b[cb + 1]), 0.f);
  r0.z = fmaxf(fmaf(dn, acc[2], b[cb + 2]), 0.f);
  r0.w = fmaxf(fmaf(dn, acc[3], b[cb + 3]), 0.f);
  r1.x = fmaxf(fmaf(dn, acc[4], b[cb + 4]), 0.f);
  r1.y = fmaxf(fmaf(dn, acc[5], b[cb + 5]), 0.f);
  r1.z = fmaxf(fmaf(dn, acc[6], b[cb + 6]), 0.f);
  r1.w = fmaxf(fmaf(dn, acc[7], b[cb + 7]), 0.f);
  ((float4*)out)[(size_t)n * 8 + q * 2 + 0] = r0;
  ((float4*)out)[(size_t)n * 8 + q * 2 + 1] = r1;
}

// ---------------- weight prep: transpose + split to bf16 hi/lo ----------------
__global__ __launch_bounds__(256) void k_prepw(const float* __restrict__ W1,
                                               const float* __restrict__ W2,
                                               unsigned short* __restrict__ Wt1h,
                                               unsigned short* __restrict__ Wt1l,
                                               unsigned short* __restrict__ Wt2h,
                                               unsigned short* __restrict__ Wt2l) {
  int o = blockIdx.x * blockDim.x + threadIdx.x;
  if (o < 256 * 192) {
    int col = o / 192, k = o % 192;
    float v = W1[k * 256 + col];
    unsigned short h = bf16r(v);
    Wt1h[o] = h;
    Wt1l[o] = bf16r(v - bf16f(h));
  } else if (o < 256 * 192 + 256 * 256) {
    int o2 = o - 256 * 192;
    int col = o2 / 256, k = o2 % 256;
    float v = W2[k * 256 + col];
    unsigned short h = bf16r(v);
    Wt2h[o2] = h;
    Wt2l[o2] = bf16r(v - bf16f(h));
  }
}

// ---------------- fused MFMA MLP (R13-exact: measured optimum 106.8us) -------
__device__ __forceinline__ float softplusf(float x) {
  return fmaxf(x, 0.f) + log1pf(expf(-fabsf(x)));
}

#define XS_STRIDE 200
#define H1_STRIDE 264
#define MNODES 80

__global__ __launch_bounds__(512, 4) void k_mlp_mfma(
    const float* __restrict__ o1, const float* __restrict__ o2,
    const float* __restrict__ o3, const float* __restrict__ o4,
    const float* __restrict__ o5, const float* __restrict__ st,
    const unsigned short* __restrict__ Wt1h, const unsigned short* __restrict__ Wt1l,
    const float* __restrict__ b1,
    const unsigned short* __restrict__ Wt2h, const unsigned short* __restrict__ Wt2l,
    const float* __restrict__ b2,
    const float* __restrict__ W3, const float* __restrict__ b3,
    float* __restrict__ conc, int N) {
  __shared__ unsigned short smem[2 * MNODES * XS_STRIDE];
  unsigned short* xsh = smem;
  unsigned short* xsl = smem + MNODES * XS_STRIDE;
  unsigned short* h1h = smem;
  float* redp = (float*)&smem[MNODES * H1_STRIDE];

  const int t = threadIdx.x;
  const int w = t >> 6;
  const int l = t & 63;
  const int l15 = l & 15, lq = l >> 4;
  const int nodeBase = blockIdx.x * MNODES;

  const float* srcs[6] = {o1, o2, o3, o4, o5, st};
  for (int i = t; i < MNODES * 96; i += 512) {
    int n = i / 96, cp = (i % 96) * 2;
    int gn = nodeBase + n;
    unsigned int pkh = 0, pkl = 0;
    if (gn < N) {
      const float* s = srcs[cp >> 5] + (size_t)gn * 32 + (cp & 31);
      float2 v = *(const float2*)s;
      unsigned short h0 = bf16r(v.x), h1_ = bf16r(v.y);
      unsigned short l0 = bf16r(v.x - bf16f(h0)), l1 = bf16r(v.y - bf16f(h1_));
      pkh = ((unsigned)h1_ << 16) | h0;
      pkl = ((unsigned)l1 << 16) | l0;
    }
    *(unsigned int*)&xsh[n * XS_STRIDE + cp] = pkh;
    *(unsigned int*)&xsl[n * XS_STRIDE + cp] = pkl;
  }
  __syncthreads();

  const int ocBase = w * 32;

  f32x4 acc[2][5];
#pragma unroll
  for (int rt = 0; rt < 2; rt++)
#pragma unroll
    for (int nt = 0; nt < 5; nt++) acc[rt][nt] = (f32x4)0.f;

  for (int kt = 0; kt < 6; kt++) {
    i32x4 ah[2], al[2];
#pragma unroll
    for (int rt = 0; rt < 2; rt++) {
      size_t aoff = (size_t)(ocBase + rt * 16 + l15) * 192 + kt * 32 + lq * 8;
      ah[rt] = *(const i32x4*)&Wt1h[aoff];
      al[rt] = *(const i32x4*)&Wt1l[aoff];
    }
#pragma unroll
    for (int nt = 0; nt < 5; nt++) {
      int boff = (nt * 16 + l15) * XS_STRIDE + kt * 32 + lq * 8;
      i32x4 bh = *(const i32x4*)&xsh[boff];
      i32x4 bl = *(const i32x4*)&xsl[boff];
#pragma unroll
      for (int rt = 0; rt < 2; rt++) mfma16(acc[rt][nt], ah[rt], bh);
#pragma unroll
      for (int rt = 0; rt < 2; rt++) mfma16(acc[rt][nt], al[rt], bh);
#pragma unroll
      for (int rt = 0; rt < 2; rt++) mfma16(acc[rt][nt], ah[rt], bl);
    }
  }
  __syncthreads();

#pragma unroll
  for (int rt = 0; rt < 2; rt++) {
    const int oc0 = ocBase + rt * 16 + lq * 4;
    float bb0 = b1[oc0], bb1 = b1[oc0 + 1], bb2 = b1[oc0 + 2], bb3 = b1[oc0 + 3];
#pragma unroll
    for (int nt = 0; nt < 5; nt++) {
      float v0 = acc[rt][nt][0] + bb0; v0 = (v0 > 0.f) ? v0 : 0.01f * v0;
      float v1 = acc[rt][nt][1] + bb1; v1 = (v1 > 0.f) ? v1 : 0.01f * v1;
      float v2 = acc[rt][nt][2] + bb2; v2 = (v2 > 0.f) ? v2 : 0.01f * v2;
      float v3 = acc[rt][nt][3] + bb3; v3 = (v3 > 0.f) ? v3 : 0.01f * v3;
      u32x2 pkh;
      pkh[0] = ((unsigned)bf16r(v1) << 16) | bf16r(v0);
      pkh[1] = ((unsigned)bf16r(v3) << 16) | bf16r(v2);
      int row = nt * 16 + l15;
      *(u32x2*)&h1h[row * H1_STRIDE + oc0] = pkh;
    }
  }
  __syncthreads();

  f32x4 acc2[2][5];
#pragma unroll
  for (int rt = 0; rt < 2; rt++)
#pragma unroll
    for (int nt = 0; nt < 5; nt++) acc2[rt][nt] = (f32x4)0.f;

  for (int kt = 0; kt < 8; kt++) {
    i32x4 ah[2], al[2];
#pragma unroll
    for (int rt = 0; rt < 2; rt++) {
      size_t aoff = (size_t)(ocBase + rt * 16 + l15) * 256 + kt * 32 + lq * 8;
      ah[rt] = *(const i32x4*)&Wt2h[aoff];
      al[rt] = *(const i32x4*)&Wt2l[aoff];
    }
#pragma unroll
    for (int nt = 0; nt < 5; nt++) {
      int boff = (nt * 16 + l15) * H1_STRIDE + kt * 32 + lq * 8;
      i32x4 bh = *(const i32x4*)&h1h[boff];
#pragma unroll
      for (int rt = 0; rt < 2; rt++) mfma16(acc2[rt][nt], ah[rt], bh);
#pragma unroll
      for (int rt = 0; rt < 2; rt++) mfma16(acc2[rt][nt], al[rt], bh);
    }
  }
  __syncthreads();

#pragma unroll
  for (int nt = 0; nt < 5; nt++) {
    float p = 0.f;
#pragma unroll
    for (int rt = 0; rt < 2; rt++) {
      const int oc0 = ocBase + rt * 16 + lq * 4;
#pragma unroll
      for (int j = 0; j < 4; j++) {
        float v = acc2[rt][nt][j] + b2[oc0 + j];
        v = (v > 0.f) ? v : 0.01f * v;
        p = fmaf(v, W3[oc0 + j], p);
      }
    }
    p += __shfl_xor(p, 16, 64);
    p += __shfl_xor(p, 32, 64);
    if (lq == 0) redp[w * MNODES + nt * 16 + l15] = p;
  }
  __syncthreads();

  if (t < MNODES) {
    int gn = nodeBase + t;
    if (gn < N) {
      float s = redp[0 * MNODES + t] + redp[1 * MNODES + t] + redp[2 * MNODES + t]
              + redp[3 * MNODES + t] + redp[4 * MNODES + t] + redp[5 * MNODES + t]
              + redp[6 * MNODES + t] + redp[7 * MNODES + t] + b3[0];
      conc[gn] = softplusf(s);
    }
  }
}

// ---------------- final normalize ----------------
__global__ __launch_bounds__(256) void k_redsum(const float* __restrict__ conc,
                                                float* __restrict__ total, int N) {
  float s = 0.f;
  for (int i = blockIdx.x * blockDim.x + threadIdx.x; i < N; i += gridDim.x * blockDim.x)
    s += conc[i];
#pragma unroll
  for (int off = 32; off > 0; off >>= 1) s += __shfl_down(s, off, 64);
  __shared__ float ws_[4];
  if ((threadIdx.x & 63) == 0) ws_[threadIdx.x >> 6] = s;
  __syncthreads();
  if (threadIdx.x == 0) atomicAdd(total, ws_[0] + ws_[1] + ws_[2] + ws_[3]);
}

__global__ __launch_bounds__(256) void k_div(const float* __restrict__ conc,
                                             const float* __restrict__ total,
                                             float* __restrict__ out, int N) {
  int i = blockIdx.x * blockDim.x + threadIdx.x;
  if (i < N) out[i] = conc[i] / (total[0] + 1e-20f);
}

extern "C" void kernel_launch(void* const* d_in, const int* in_sizes, int n_in,
                              void* d_out, int out_size, void* d_ws, size_t ws_size,
                              hipStream_t stream) {
  const float* state = (const float*)d_in[0];
  const int*   ei    = (const int*)d_in[1];
  const float* cW1 = (const float*)d_in[2];
  const float* cb1 = (const float*)d_in[3];
  const float* cW2 = (const float*)d_in[4];
  const float* cb2 = (const float*)d_in[5];
  const float* cW3 = (const float*)d_in[6];
  const float* cb3 = (const float*)d_in[7];
  const float* lW1 = (const float*)d_in[8];
  const float* lb1 = (const float*)d_in[9];
  const float* lW2 = (const float*)d_in[10];
  const float* lb2 = (const float*)d_in[11];
  const float* lW3 = (const float*)d_in[12];
  const float* lb3 = (const float*)d_in[13];

  const int N = in_sizes[0] / 32;
  const int E = in_sizes[1] / 2;
  const int* srcI = ei;
  const int* dstI = ei + E;
  const int nbuck = CDIV(N, BUCK_W);
  const int chunk = CDIV(E, NBLK1);

  char* w = (char*)d_ws;
  size_t off = 0;
  auto alloc = [&](size_t bytes) -> void* {
    void* p = w + off;
    off = (off + bytes + 255) & ~(size_t)255;
    return p;
  };
  int*   cnt       = (int*)alloc((size_t)N * 4);
  float* total     = (float*)alloc(256);
  size_t zbytes = off;  // cnt + total zeroed
  int*   rowptr    = (int*)alloc(((size_t)N + 1) * 4);
  int*   blockSums = (int*)alloc(256 * 4);
  int*   colidx    = (int*)alloc((size_t)E * 4);
  float* dinv      = (float*)alloc((size_t)N * 4);
  int*   hist      = (int*)alloc((size_t)NBLK1 * nbuck * 4);
  int*   pbase     = (int*)alloc((size_t)nbuck * 256 * 4);
  int*   btotal    = (int*)alloc((size_t)nbuck * 4);
  int*   bbase     = (int*)alloc(((size_t)nbuck + 1) * 4);
  int2*  bkt       = (int2*)alloc((size_t)E * 8);
  unsigned short* ybuf = (unsigned short*)alloc((size_t)N * 32 * 2);
  float* out1      = (float*)alloc((size_t)N * 32 * 4);
  float* out2      = (float*)alloc((size_t)N * 32 * 4);
  float* out3      = (float*)alloc((size_t)N * 32 * 4);
  float* out4      = (float*)alloc((size_t)N * 32 * 4);
  float* out5      = (float*)alloc((size_t)N * 32 * 4);
  float* conc      = (float*)alloc((size_t)N * 4);
  unsigned short* Wt1h = (unsigned short*)alloc(256 * 192 * 2);
  unsigned short* Wt1l = (unsigned short*)alloc(256 * 192 * 2);
  unsigned short* Wt2h = (unsigned short*)alloc(256 * 256 * 2);
  unsigned short* Wt2l = (unsigned short*)alloc(256 * 256 * 2);

  const int TB = 256;
  hipMemsetAsync(d_ws, 0, zbytes, stream);

  k_count<<<CDIV(E, TB), TB, 0, stream>>>(dstI, cnt, E);
  int NB = CDIV(N, 1024);
  k_scan1<<<NB, TB, 0, stream>>>(cnt, rowptr, blockSums, N);
  k_scan2<<<1, TB, 0, stream>>>(blockSums, NB);
  k_scan3<<<CDIV(N, TB), TB, 0, stream>>>(rowptr, blockSums, N, E);
  k_dinv<<<CDIV(N, TB), TB, 0, stream>>>(cnt, dinv, N);

  k_p1hist<<<NBLK1, TB, 0, stream>>>(dstI, hist, E, nbuck, chunk);
  k_pscan<<<nbuck, TB, 0, stream>>>(hist, pbase, btotal, nbuck);
  k_pscan2<<<1, 1024, 0, stream>>>(btotal, bbase, nbuck, E);
  k_p1scatter<<<NBLK1, TB, 0, stream>>>(srcI, dstI, pbase, bbase, bkt, E, nbuck, chunk);
  k_p2build<<<nbuck, TB, 0, stream>>>(bkt, bbase, rowptr, colidx, N);

  k_prepw<<<CDIV(256 * 192 + 256 * 256, TB), TB, 0, stream>>>(lW1, lW2, Wt1h, Wt1l, Wt2h, Wt2l);

  struct Layer { const float* x; const float* W; const float* b; float* out; };
  Layer L[5] = {{state, cW1, cb1, out1},
                {out1,  cW2, cb2, out2},
                {out2,  cW3, cb3, out3},
                {out3,  cW3, cb3, out4},
                {out4,  cW3, cb3, out5}};
  for (int i = 0; i < 5; i++) {
    k_xw<<<CDIV(N * 16, TB), TB, 0, stream>>>(L[i].x, L[i].W, dinv, ybuf, N);
    k_agg<<<CDIV(N, 64), TB, 0, stream>>>(ybuf, rowptr, colidx, dinv, L[i].b, L[i].out, N);
  }

  k_mlp_mfma<<<CDIV(N, MNODES), 512, 0, stream>>>(out1, out2, out3, out4, out5, state,
                                                  Wt1h, Wt1l, lb1, Wt2h, Wt2l, lb2,
                                                  lW3, lb3, conc, N);
  k_redsum<<<256, TB, 0, stream>>>(conc, total, N);
  k_div<<<CDIV(N, TB), TB, 0, stream>>>(conc, total, (float*)d_out, N);
}